// Round 3
// baseline (2644.505 us; speedup 1.0000x reference)
//
#include <hip/hip_runtime.h>

#define N_ITEMS 20000
#define N_USERS 2048
#define NNZ     4000000
#define LDP     2112          // padded XT leading dim (66 cache lines: breaks L2 set aliasing)
#define HALF_ITEMS 10000
#define NBINS   (2 * N_ITEMS) // (row, c-half) bins

// ---------------- ws layout (bytes) ----------------
#define OFF_XT      ((size_t)0)                       // bf16 [N_ITEMS][LDP] = 84,480,000
#define OFF_CSRPK   ((size_t)84480000)                // u32 [NNZ] (bf16 val | c_local) = 16,000,000
#define OFF_ROWPTR  (OFF_CSRPK + 16000000)            // int [NBINS+1] -> 160,256
#define OFF_CURSOR  (OFF_ROWPTR + 160256)             // int [NBINS]
#define OFF_CNT     (OFF_CURSOR + 160256)             // int [NBINS]
#define OFF_BSUM    (OFF_CNT + 160256)                // int [64]

static __device__ __forceinline__ unsigned short f2bf(float f) {
  unsigned u = __float_as_uint(f);
  unsigned r = (u + 0x7fffu + ((u >> 16) & 1u)) >> 16;
  return (unsigned short)r;
}

// X [N_USERS][N_ITEMS] f32  ->  XT [N_ITEMS][LDP] bf16 (padded)
__global__ __launch_bounds__(256) void transpose_kernel(
    const float* __restrict__ X, unsigned short* __restrict__ XT) {
  __shared__ float tile[64][65];
  int k0 = blockIdx.x * 64;
  int u0 = blockIdx.y * 64;
  int lane = threadIdx.x & 63;
  int dq = threadIdx.x >> 6;
  #pragma unroll
  for (int m = 0; m < 16; ++m) {
    int u = u0 + dq + 4 * m;
    int k = k0 + lane;
    float v = 0.f;
    if (k < N_ITEMS) v = X[(size_t)u * N_ITEMS + k];
    tile[lane][dq + 4 * m] = v;
  }
  __syncthreads();
  #pragma unroll
  for (int m = 0; m < 16; ++m) {
    int k = k0 + dq + 4 * m;
    if (k < N_ITEMS)
      XT[(size_t)k * LDP + u0 + lane] = f2bf(tile[dq + 4 * m][lane]);
  }
}

__global__ void zero_kernel(int* __restrict__ p, int n) {
  int i = blockIdx.x * blockDim.x + threadIdx.x;
  if (i < n) p[i] = 0;
}

__global__ void count_kernel(const int* __restrict__ rows, const int* __restrict__ cols,
                             int* __restrict__ cnt) {
  int i = blockIdx.x * blockDim.x + threadIdx.x;
  if (i < NNZ) {
    int bin = 2 * rows[i] + (cols[i] >= HALF_ITEMS ? 1 : 0);
    atomicAdd(&cnt[bin], 1);
  }
}

// 2-level scan over NBINS
__global__ __launch_bounds__(1024) void scan1_kernel(
    const int* __restrict__ cnt, int* __restrict__ loc, int* __restrict__ bsum) {
  __shared__ int buf[1024];
  int tid = threadIdx.x;
  int i = blockIdx.x * 1024 + tid;
  int x = (i < NBINS) ? cnt[i] : 0;
  buf[tid] = x;
  __syncthreads();
  for (int off = 1; off < 1024; off <<= 1) {
    int y = (tid >= off) ? buf[tid - off] : 0;
    __syncthreads();
    buf[tid] += y;
    __syncthreads();
  }
  if (i < NBINS) loc[i] = buf[tid] - x;
  if (tid == 1023) bsum[blockIdx.x] = buf[1023];
}

__global__ void scan2_kernel(int* __restrict__ bsum, int nblk) {
  if (threadIdx.x == 0) {
    int s = 0;
    for (int b = 0; b < nblk; ++b) { int t = bsum[b]; bsum[b] = s; s += t; }
  }
}

__global__ __launch_bounds__(1024) void scan3_kernel(
    int* __restrict__ row_ptr, const int* __restrict__ bsum, int* __restrict__ cursor) {
  int i = blockIdx.x * 1024 + threadIdx.x;
  if (i < NBINS) {
    int v = row_ptr[i] + bsum[blockIdx.x];
    row_ptr[i] = v;
    cursor[i] = v;
  }
  if (i == 0) row_ptr[NBINS] = NNZ;
}

__global__ void scatter_kernel(const int* __restrict__ rows, const int* __restrict__ cols,
                               const float* __restrict__ vals, int* __restrict__ cursor,
                               unsigned* __restrict__ csr_pk) {
  int i = blockIdx.x * blockDim.x + threadIdx.x;
  if (i < NNZ) {
    int c = cols[i];
    int h = (c >= HALF_ITEMS) ? 1 : 0;
    int bin = 2 * rows[i] + h;
    int pos = atomicAdd(&cursor[bin], 1);
    csr_pk[pos] = (unsigned)(c - h * HALF_ITEMS) | ((unsigned)f2bf(vals[i]) << 16);
  }
}

// Out[u,r] += sum_{j in (r,half)} val(j) * XT[col(j)][u]
// WG: 256 thr = 4 waves; 16 rows x 128 users (2 users/lane via dword gather).
// grid = 1250 r_blocks * 16 u_chunks * 2 halves. xcd = wg&7 owns gcombo
// 4*xcd..4*xcd+3, each = (uchunk, half); r-sweep keeps the 2.56 MB XT
// (half,uchunk)-slice resident in that XCD's L2.
// Exactly 2 atomic adds per out element (one per half) onto zeroed out ->
// bitwise-deterministic (f32 add is commutative).
__global__ __launch_bounds__(256) void spmm_kernel(
    const int* __restrict__ row_ptr, const unsigned* __restrict__ csr_pk,
    const unsigned short* __restrict__ xt, float* __restrict__ out) {
  __shared__ float tile[16][130];
  int wg = blockIdx.x;
  int xcd = wg & 7;
  int slot = wg >> 3;            // [0, 5000)
  int combo = slot / 1250;       // [0, 4)
  int rb = slot - combo * 1250;  // [0, 1250)
  int gcombo = xcd * 4 + combo;  // [0, 32)
  int uchunk = gcombo >> 1;
  int half = gcombo & 1;
  int u0 = uchunk * 128;
  int r0 = rb * 16;
  int lane = threadIdx.x & 63;
  int wave = __builtin_amdgcn_readfirstlane((int)(threadIdx.x >> 6));

  const unsigned short* xt_h = xt + (size_t)half * HALF_ITEMS * LDP + u0 + 2 * lane;

  for (int rr = 0; rr < 4; ++rr) {
    int r = r0 + wave * 4 + rr;
    int seg = 2 * r + half;
    int jb = __builtin_amdgcn_readfirstlane(row_ptr[seg]);
    int je = __builtin_amdgcn_readfirstlane(row_ptr[seg + 1]);
    float accx = 0.f, accy = 0.f, accz = 0.f, accw = 0.f;
    int j = jb;
    for (; j + 8 <= je; j += 8) {
      unsigned e[8];
      #pragma unroll
      for (int k = 0; k < 8; ++k) e[k] = csr_pk[j + k];
      unsigned x2[8];
      #pragma unroll
      for (int k = 0; k < 8; ++k)
        x2[k] = *reinterpret_cast<const unsigned*>(xt_h + (e[k] & 0x3fffu) * LDP);
      #pragma unroll
      for (int k = 0; k < 8; ++k) {
        float v = __uint_as_float(e[k] & 0xffff0000u);
        float xlo = __uint_as_float(x2[k] << 16);
        float xhi = __uint_as_float(x2[k] & 0xffff0000u);
        if (k & 1) { accz = fmaf(v, xlo, accz); accw = fmaf(v, xhi, accw); }
        else       { accx = fmaf(v, xlo, accx); accy = fmaf(v, xhi, accy); }
      }
    }
    for (; j < je; ++j) {
      unsigned e = csr_pk[j];
      unsigned x2 = *reinterpret_cast<const unsigned*>(xt_h + (e & 0x3fffu) * LDP);
      float v = __uint_as_float(e & 0xffff0000u);
      accx = fmaf(v, __uint_as_float(x2 << 16), accx);
      accy = fmaf(v, __uint_as_float(x2 & 0xffff0000u), accy);
    }
    float2 acc;
    acc.x = accx + accz;  // user u0 + 2*lane
    acc.y = accy + accw;  // user u0 + 2*lane + 1
    *reinterpret_cast<float2*>(&tile[wave * 4 + rr][2 * lane]) = acc;
  }
  __syncthreads();
  // atomic-add [128u x 16r] tile; thread t -> (ul = t>>1, rseg = (t&1)*8).
  // out line (64B) per user covers exactly items [r0, r0+16).
  int ul = threadIdx.x >> 1;
  int rseg = (threadIdx.x & 1) * 8;
  float* op = &out[(size_t)(u0 + ul) * N_ITEMS + r0 + rseg];
  #pragma unroll
  for (int i = 0; i < 8; ++i) atomicAdd(&op[i], tile[rseg + i][ul]);
}

extern "C" void kernel_launch(void* const* d_in, const int* in_sizes, int n_in,
                              void* d_out, int out_size, void* d_ws, size_t ws_size,
                              hipStream_t stream) {
  const float* X      = (const float*)d_in[0];
  const float* S_vals = (const float*)d_in[1];
  const int*   S_rows = (const int*)d_in[2];
  const int*   S_cols = (const int*)d_in[3];
  float* out = (float*)d_out;

  char* ws = (char*)d_ws;
  unsigned short* XT  = (unsigned short*)(ws + OFF_XT);
  unsigned* csr_pk    = (unsigned*)(ws + OFF_CSRPK);
  int* row_ptr        = (int*)(ws + OFF_ROWPTR);
  int* cursor         = (int*)(ws + OFF_CURSOR);
  int* cnt            = (int*)(ws + OFF_CNT);
  int* bsum           = (int*)(ws + OFF_BSUM);

  const int nblk = (NBINS + 1023) / 1024;  // 40

  transpose_kernel<<<dim3((N_ITEMS + 63) / 64, N_USERS / 64), 256, 0, stream>>>(X, XT);
  zero_kernel<<<(NBINS + 255) / 256, 256, 0, stream>>>(cnt, NBINS);
  count_kernel<<<NNZ / 256, 256, 0, stream>>>(S_rows, S_cols, cnt);
  scan1_kernel<<<nblk, 1024, 0, stream>>>(cnt, row_ptr, bsum);
  scan2_kernel<<<1, 64, 0, stream>>>(bsum, nblk);
  scan3_kernel<<<nblk, 1024, 0, stream>>>(row_ptr, bsum, cursor);
  scatter_kernel<<<NNZ / 256, 256, 0, stream>>>(S_rows, S_cols, S_vals, cursor, csr_pk);
  hipMemsetAsync(d_out, 0, (size_t)N_USERS * N_ITEMS * sizeof(float), stream);
  spmm_kernel<<<1250 * 32, 256, 0, stream>>>(row_ptr, csr_pk, XT, out);
}

// Round 5
// 1260.501 us; speedup vs baseline: 2.0980x; 2.0980x over previous
//
#include <hip/hip_runtime.h>

#define N_ITEMS 20000
#define N_USERS 2048
#define NNZ     4000000
#define LDP     2112   // padded XT leading dim (66 cache lines: breaks L2/L3 set aliasing)

typedef float f32x4 __attribute__((ext_vector_type(4)));

// ---------------- ws layout (bytes) ----------------
#define OFF_XT      ((size_t)0)                 // bf16 [N_ITEMS][LDP] = 84,480,000
#define OFF_CSRPK   ((size_t)84480000)          // u32 [NNZ] (bf16 val | 15-bit col) = 16,000,000
#define OFF_ROWPTR  (OFF_CSRPK + 16000000)      // int [N_ITEMS+1] -> 80,128
#define OFF_CURSOR  (OFF_ROWPTR + 80128)        // int [N_ITEMS]
#define OFF_CNT     (OFF_CURSOR + 80128)        // int [N_ITEMS]
#define OFF_BSUM    (OFF_CNT + 80128)           // int [64]

static __device__ __forceinline__ unsigned short f2bf(float f) {
  unsigned u = __float_as_uint(f);
  unsigned r = (u + 0x7fffu + ((u >> 16) & 1u)) >> 16;
  return (unsigned short)r;
}

// X [N_USERS][N_ITEMS] f32  ->  XT [N_ITEMS][LDP] bf16 (padded)
__global__ __launch_bounds__(256) void transpose_kernel(
    const float* __restrict__ X, unsigned short* __restrict__ XT) {
  __shared__ float tile[64][65];
  int k0 = blockIdx.x * 64;
  int u0 = blockIdx.y * 64;
  int lane = threadIdx.x & 63;
  int dq = threadIdx.x >> 6;
  #pragma unroll
  for (int m = 0; m < 16; ++m) {
    int u = u0 + dq + 4 * m;
    int k = k0 + lane;
    float v = 0.f;
    if (k < N_ITEMS) v = X[(size_t)u * N_ITEMS + k];
    tile[lane][dq + 4 * m] = v;
  }
  __syncthreads();
  #pragma unroll
  for (int m = 0; m < 16; ++m) {
    int k = k0 + dq + 4 * m;
    if (k < N_ITEMS)
      XT[(size_t)k * LDP + u0 + lane] = f2bf(tile[dq + 4 * m][lane]);
  }
}

__global__ void zero_kernel(int* __restrict__ p, int n) {
  int i = blockIdx.x * blockDim.x + threadIdx.x;
  if (i < n) p[i] = 0;
}

__global__ void count_kernel(const int* __restrict__ rows, int* __restrict__ cnt) {
  int i = blockIdx.x * blockDim.x + threadIdx.x;
  if (i < NNZ) atomicAdd(&cnt[rows[i]], 1);
}

// 2-level scan over N_ITEMS
__global__ __launch_bounds__(1024) void scan1_kernel(
    const int* __restrict__ cnt, int* __restrict__ loc, int* __restrict__ bsum) {
  __shared__ int buf[1024];
  int tid = threadIdx.x;
  int i = blockIdx.x * 1024 + tid;
  int x = (i < N_ITEMS) ? cnt[i] : 0;
  buf[tid] = x;
  __syncthreads();
  for (int off = 1; off < 1024; off <<= 1) {
    int y = (tid >= off) ? buf[tid - off] : 0;
    __syncthreads();
    buf[tid] += y;
    __syncthreads();
  }
  if (i < N_ITEMS) loc[i] = buf[tid] - x;
  if (tid == 1023) bsum[blockIdx.x] = buf[1023];
}

__global__ void scan2_kernel(int* __restrict__ bsum, int nblk) {
  if (threadIdx.x == 0) {
    int s = 0;
    for (int b = 0; b < nblk; ++b) { int t = bsum[b]; bsum[b] = s; s += t; }
  }
}

__global__ __launch_bounds__(1024) void scan3_kernel(
    int* __restrict__ row_ptr, const int* __restrict__ bsum, int* __restrict__ cursor) {
  int i = blockIdx.x * 1024 + threadIdx.x;
  if (i < N_ITEMS) {
    int v = row_ptr[i] + bsum[blockIdx.x];
    row_ptr[i] = v;
    cursor[i] = v;
  }
  if (i == 0) row_ptr[N_ITEMS] = NNZ;
}

__global__ void scatter_kernel(const int* __restrict__ rows, const int* __restrict__ cols,
                               const float* __restrict__ vals, int* __restrict__ cursor,
                               unsigned* __restrict__ csr_pk) {
  int i = blockIdx.x * blockDim.x + threadIdx.x;
  if (i < NNZ) {
    int r = rows[i];
    int pos = atomicAdd(&cursor[r], 1);
    csr_pk[pos] = (unsigned)cols[i] | ((unsigned)f2bf(vals[i]) << 16);
  }
}

// Out[u,r] = sum_j val(j) * XT[col(j)][u]
// WG: 256 thr = 4 waves; 16 rows x 128 users (2 users/lane, dword gathers).
// grid = 1250 rb * 16 uchunks; xcd = wg&7 owns uchunks {2x, 2x+1}.
// Per-gather: 256B coalesced from a random padded row; L2 sees 16.4 GB total
// (the hard floor); L3 holds all of XT (padding prevents set aliasing) so
// HBM refetch ~ 0. Plain nt stores, exactly one write per output element.
__global__ __launch_bounds__(256) void spmm_kernel(
    const int* __restrict__ row_ptr, const unsigned* __restrict__ csr_pk,
    const unsigned short* __restrict__ xt, float* __restrict__ out) {
  __shared__ float tile[16][132];
  int wg = blockIdx.x;
  int xcd = wg & 7;
  int slot = wg >> 3;            // [0, 2500)
  int combo = slot / 1250;       // 0..1
  int rb = slot - combo * 1250;  // [0, 1250)
  int uchunk = xcd * 2 + combo;
  int u0 = uchunk * 128;
  int r0 = rb * 16;
  int lane = threadIdx.x & 63;
  int wave = __builtin_amdgcn_readfirstlane((int)(threadIdx.x >> 6));
  const unsigned short* xt_u = xt + u0 + 2 * lane;

#define PROC8(E)                                                         \
  {                                                                      \
    unsigned x2[8];                                                      \
    _Pragma("unroll")                                                    \
    for (int k = 0; k < 8; ++k)                                          \
      x2[k] = *reinterpret_cast<const unsigned*>(xt_u + (E[k] & 0x7fffu) * LDP); \
    _Pragma("unroll")                                                    \
    for (int k = 0; k < 8; ++k) {                                        \
      float v  = __uint_as_float(E[k] & 0xffff0000u);                    \
      float xl = __uint_as_float(x2[k] << 16);                           \
      float xh = __uint_as_float(x2[k] & 0xffff0000u);                   \
      if (k & 1) { a2 = fmaf(v, xl, a2); a3 = fmaf(v, xh, a3); }         \
      else       { a0 = fmaf(v, xl, a0); a1 = fmaf(v, xh, a1); }         \
    }                                                                    \
  }

  #pragma unroll
  for (int rr = 0; rr < 4; ++rr) {
    int r = r0 + wave * 4 + rr;
    int jb = __builtin_amdgcn_readfirstlane(row_ptr[r]);
    int je = __builtin_amdgcn_readfirstlane(row_ptr[r + 1]);
    float a0 = 0.f, a1 = 0.f, a2 = 0.f, a3 = 0.f;
    int n8 = (je - jb) >> 3;
    if (n8 > 0) {
      unsigned e[8];
      #pragma unroll
      for (int k = 0; k < 8; ++k) e[k] = csr_pk[jb + k];
      // software pipeline: prefetch next 8-batch while gathering current
      for (int b = 1; b < n8; ++b) {
        unsigned en[8];
        int jn = jb + b * 8;
        #pragma unroll
        for (int k = 0; k < 8; ++k) en[k] = csr_pk[jn + k];
        PROC8(e)
        #pragma unroll
        for (int k = 0; k < 8; ++k) e[k] = en[k];
      }
      PROC8(e)
    }
    for (int j = jb + n8 * 8; j < je; ++j) {
      unsigned ee = csr_pk[j];
      unsigned x2 = *reinterpret_cast<const unsigned*>(xt_u + (ee & 0x7fffu) * LDP);
      float v = __uint_as_float(ee & 0xffff0000u);
      a0 = fmaf(v, __uint_as_float(x2 << 16), a0);
      a1 = fmaf(v, __uint_as_float(x2 & 0xffff0000u), a1);
    }
    tile[wave * 4 + rr][2 * lane]     = a0 + a2;  // user u0 + 2*lane
    tile[wave * 4 + rr][2 * lane + 1] = a1 + a3;  // user u0 + 2*lane + 1
  }
#undef PROC8
  __syncthreads();
  // store [128u x 16r] tile; thread t -> (ul = t>>1, rseg = (t&1)*8).
  int ul = threadIdx.x >> 1;
  int rseg = (threadIdx.x & 1) * 8;
  float* op = &out[(size_t)(u0 + ul) * N_ITEMS + r0 + rseg];
  f32x4 o0, o1;
  o0.x = tile[rseg + 0][ul]; o0.y = tile[rseg + 1][ul];
  o0.z = tile[rseg + 2][ul]; o0.w = tile[rseg + 3][ul];
  o1.x = tile[rseg + 4][ul]; o1.y = tile[rseg + 5][ul];
  o1.z = tile[rseg + 6][ul]; o1.w = tile[rseg + 7][ul];
  __builtin_nontemporal_store(o0, reinterpret_cast<f32x4*>(op));
  __builtin_nontemporal_store(o1, reinterpret_cast<f32x4*>(op) + 1);
}

extern "C" void kernel_launch(void* const* d_in, const int* in_sizes, int n_in,
                              void* d_out, int out_size, void* d_ws, size_t ws_size,
                              hipStream_t stream) {
  const float* X      = (const float*)d_in[0];
  const float* S_vals = (const float*)d_in[1];
  const int*   S_rows = (const int*)d_in[2];
  const int*   S_cols = (const int*)d_in[3];
  float* out = (float*)d_out;

  char* ws = (char*)d_ws;
  unsigned short* XT  = (unsigned short*)(ws + OFF_XT);
  unsigned* csr_pk    = (unsigned*)(ws + OFF_CSRPK);
  int* row_ptr        = (int*)(ws + OFF_ROWPTR);
  int* cursor         = (int*)(ws + OFF_CURSOR);
  int* cnt            = (int*)(ws + OFF_CNT);
  int* bsum           = (int*)(ws + OFF_BSUM);

  const int nblk = (N_ITEMS + 1023) / 1024;  // 20

  transpose_kernel<<<dim3((N_ITEMS + 63) / 64, N_USERS / 64), 256, 0, stream>>>(X, XT);
  zero_kernel<<<(N_ITEMS + 255) / 256, 256, 0, stream>>>(cnt, N_ITEMS);
  count_kernel<<<NNZ / 256, 256, 0, stream>>>(S_rows, cnt);
  scan1_kernel<<<nblk, 1024, 0, stream>>>(cnt, row_ptr, bsum);
  scan2_kernel<<<1, 64, 0, stream>>>(bsum, nblk);
  scan3_kernel<<<nblk, 1024, 0, stream>>>(row_ptr, bsum, cursor);
  scatter_kernel<<<NNZ / 256, 256, 0, stream>>>(S_rows, S_cols, S_vals, cursor, csr_pk);
  spmm_kernel<<<1250 * 16, 256, 0, stream>>>(row_ptr, csr_pk, XT, out);
}